// Round 9
// baseline (209.763 us; speedup 1.0000x reference)
//
#include <hip/hip_runtime.h>
#include <hip/hip_bf16.h>

// Problem constants (S4Layer: T=4096, B=16, D=128, S=256)
#define T_  4096
#define B_  16
#define D_  128
#define S_  256
#define WND 64             // chunk length = per-block t-tile
#define C4  (T_/WND)       // 64 chunks; grid = 64 x 16 = 1024 = 4/CU x 256 CU

using bf8   = __attribute__((ext_vector_type(8))) short;   // 8 bf16 (4 VGPRs)
using f32x4 = __attribute__((ext_vector_type(4))) float;   // MFMA acc

__device__ inline float bfbits(unsigned short h) {
    return __builtin_bit_cast(float, (unsigned)h << 16);
}
__device__ inline unsigned short bf16bits(float f) {
    return __hip_bfloat16_raw(__float2bfloat16(f)).x;
}

// ---------------- K1: parameters -------------------------------------------
__global__ __launch_bounds__(256) void k_params(
        const float* __restrict__ lna, const float* __restrict__ bmat,
        const float* __restrict__ ldt,
        float* __restrict__ abar, float* __restrict__ a64,
        __hip_bfloat16* __restrict__ bbar) {
    if (blockIdx.x < 128) {
        int idx = blockIdx.x * 256 + threadIdx.x;   // (s,d)
        int s = idx >> 7;
        float la = fminf(fmaxf(lna[s], -8.f), 4.f);
        float ar = -expf(la);
        float lt = fminf(fmaxf(ldt[s], -8.f), 1.f);
        float dt = expf(lt);
        float xx = dt * ar;
        float ratio = (fabsf(xx) < 1e-6f) ? dt : (expm1f(xx) / ar);
        bbar[idx] = __float2bfloat16(ratio * bmat[idx]);
    } else {
        int s = threadIdx.x;
        float la = fminf(fmaxf(lna[s], -8.f), 4.f);
        float ar = -expf(la);
        float lt = fminf(fmaxf(ldt[s], -8.f), 1.f);
        float dt = expf(lt);
        float ab = expf(dt * ar);
        abar[s] = ab;
        float p = ab;
#pragma unroll
        for (int j = 0; j < 6; ++j) p *= p;     // a^64 by squaring
        a64[s] = p;
    }
}

// ---------------- K2 (fused): GEMM -> e64 publish -> carry -> scan -> out --
// Block (c,b): P[t'][s] stays in LDS. e64 partial published with an
// agent-scope release flag; carry consumes predecessors' partials with a
// fixed-trip predicated Horner. Grid = 1024 blocks, all co-resident
// (4 blocks/CU: 32 KiB LDS, <=128 VGPR), deps strictly lower block id.
__global__ __launch_bounds__(256, 4) void k_fused(
        const float* __restrict__ x, const __hip_bfloat16* __restrict__ bbar,
        const float* __restrict__ abar, const float* __restrict__ a64,
        const float* __restrict__ z0, float* __restrict__ e64,
        unsigned* __restrict__ flags, float* __restrict__ out) {
    const int c = blockIdx.x, b = blockIdx.y;
    __shared__ char LDS[WND * 512];    // 32 KiB: A-stage in [0,16K), then P
    const int tid = threadIdx.x, lane = tid & 63, w = tid >> 6;
    const int l15 = lane & 15, l4 = lane >> 4;

    // ---- stage A: rows t'=0..63 of batch b, fp32 -> bf16, swizzled --------
#pragma unroll
    for (int k = 0; k < 8; ++k) {
        int idx = tid + k * 256;
        int row = idx >> 5, seg = idx & 31;
        float4 v = *(const float4*)(x + ((size_t)(c * WND + row) * B_ + b) * D_ + seg * 4);
        __hip_bfloat162 lo = __float22bfloat162_rn(make_float2(v.x, v.y));
        __hip_bfloat162 hi = __float22bfloat162_rn(make_float2(v.z, v.w));
        uint2 pk = { *(unsigned*)&lo, *(unsigned*)&hi };
        int off = (row * 256 + seg * 8) ^ ((row & 7) << 4);
        *(uint2*)(LDS + off) = pk;
    }
    __syncthreads();

    // ---- MFMA: wave w owns s in [w*64,(w+1)*64); acc row = i*16+l4*4+r ----
    f32x4 acc[4][4] = {};
    for (int j = 0; j < 4; ++j) {
        bf8 bfrag[4];
        int s = w * 64 + j * 16 + l15;
#pragma unroll
        for (int kk = 0; kk < 4; ++kk)
            bfrag[kk] = *(const bf8*)((const short*)bbar + s * D_ + kk * 32 + l4 * 8);
#pragma unroll
        for (int i = 0; i < 4; ++i) {
            bf8 af[4];
            int tr = i * 16 + l15;
#pragma unroll
            for (int kk = 0; kk < 4; ++kk) {
                int off = (tr * 256 + kk * 64 + l4 * 16) ^ ((tr & 7) << 4);
                af[kk] = *(const bf8*)(LDS + off);
            }
#pragma unroll
            for (int kk = 0; kk < 4; ++kk)
                acc[i][j] = __builtin_amdgcn_mfma_f32_16x16x32_bf16(
                                af[kk], bfrag[kk], acc[i][j], 0, 0, 0);
        }
    }
    __syncthreads();   // all A reads done; LDS becomes P[t'][s] bf16

    // ---- e64 Horner (bf16-rounded) + P -> LDS (swizzled) ------------------
    // t' = i*16 + l4*4 + r ; weight a^(63-t') = a^(3-r)*a^(16(3-i))*a^(4(3-l4))
#pragma unroll
    for (int j = 0; j < 4; ++j) {
        int s = w * 64 + j * 16 + l15;
        float a  = abar[s];
        float a2 = a * a, a4 = a2 * a2, a8 = a4 * a4, a16 = a8 * a8;
        float lf = (l4 == 0) ? a8 * a4 : (l4 == 1) ? a8 : (l4 == 2) ? a4 : 1.f;
        float e = 0.f;
#pragma unroll
        for (int i = 0; i < 4; ++i) {
            unsigned short h0 = bf16bits(acc[i][j][0]);
            unsigned short h1 = bf16bits(acc[i][j][1]);
            unsigned short h2 = bf16bits(acc[i][j][2]);
            unsigned short h3 = bf16bits(acc[i][j][3]);
            float inner = bfbits(h0);
            inner = fmaf(inner, a, bfbits(h1));
            inner = fmaf(inner, a, bfbits(h2));
            inner = fmaf(inner, a, bfbits(h3));
            e = fmaf(e, a16, inner);
            int row0 = i * 16 + l4 * 4;            // ((row>>2)&3) == l4 here
            *(unsigned short*)(LDS + (((row0    ) * 512 + s * 2) ^ (l4 << 5))) = h0;
            *(unsigned short*)(LDS + (((row0 + 1) * 512 + s * 2) ^ (l4 << 5))) = h1;
            *(unsigned short*)(LDS + (((row0 + 2) * 512 + s * 2) ^ (l4 << 5))) = h2;
            *(unsigned short*)(LDS + (((row0 + 3) * 512 + s * 2) ^ (l4 << 5))) = h3;
        }
        e *= lf;
        e += __shfl_xor(e, 16);
        e += __shfl_xor(e, 32);
        if (l4 == 0) e64[((size_t)c * B_ + b) * S_ + s] = e;
    }

    // ---- publish: device-scope release of this block's e64 partial --------
    __threadfence();
    __syncthreads();
    if (tid == 0)
        __hip_atomic_store(&flags[b * C4 + c], 1u,
                           __ATOMIC_RELEASE, __HIP_MEMORY_SCOPE_AGENT);

    // ---- spin-acquire on predecessor chunk flags (strictly lower ids) -----
    if (tid < c) {
        const unsigned* f = &flags[b * C4 + tid];
        while (__hip_atomic_load(f, __ATOMIC_ACQUIRE,
                                 __HIP_MEMORY_SCOPE_AGENT) == 0u)
            __builtin_amdgcn_s_sleep(1);
    }
    __syncthreads();
    __threadfence();

    // ---- carry: fixed-trip predicated Horner over predecessor partials ----
    const int s = tid;
    float z = z0[b * S_ + s];
    {
        const float aw = a64[s];
#pragma unroll
        for (int cp0 = 0; cp0 < C4; cp0 += 16) {
            float ev[16];
#pragma unroll
            for (int k = 0; k < 16; ++k)
                ev[k] = __hip_atomic_load(
                            &e64[((size_t)(cp0 + k) * B_ + b) * S_ + s],
                            __ATOMIC_RELAXED, __HIP_MEMORY_SCOPE_AGENT);
#pragma unroll
            for (int k = 0; k < 16; ++k) {
                float zn = fmaf(aw, z, ev[k]);
                z = (cp0 + k < c) ? zn : z;     // garbage beyond c discarded
            }
        }
    }

    // ---- scan own P tile from LDS, coalesced streaming out ----------------
    {
        const float a = abar[s];
        float* op = out + ((size_t)(c * WND) * B_ + b) * S_ + s;
#pragma unroll 8
        for (int t = 0; t < WND; ++t) {
            unsigned short h =
                *(unsigned short*)(LDS + ((t * 512 + s * 2) ^ (((t >> 2) & 3) << 5)));
            z = fmaf(a, z, bfbits(h));
            __builtin_nontemporal_store(z, op);
            op += (size_t)B_ * S_;
        }
    }
}

extern "C" void kernel_launch(void* const* d_in, const int* in_sizes, int n_in,
                              void* d_out, int out_size, void* d_ws, size_t ws_size,
                              hipStream_t stream) {
    const float* x   = (const float*)d_in[0];  // [T,B,D]
    const float* z0  = (const float*)d_in[1];  // [B,S]
    const float* lna = (const float*)d_in[2];  // [S]
    const float* bm  = (const float*)d_in[3];  // [S,D]
    const float* ldt = (const float*)d_in[4];  // [S]
    float* out = (float*)d_out;

    char* ws = (char*)d_ws;
    float*          abar  = (float*)ws;                        // 1 KiB
    float*          a64   = (float*)(ws + 4096);               // 1 KiB
    __hip_bfloat16* bbar  = (__hip_bfloat16*)(ws + 8192);      // 64 KiB
    float*          e64   = (float*)(ws + (128 << 10));        // 1 MiB [c][b][s]
    unsigned*       flags = (unsigned*)(ws + (2 << 20));       // 4 KiB [b][c]

    hipMemsetAsync(flags, 0, B_ * C4 * sizeof(unsigned), stream);
    k_params<<<129, 256, 0, stream>>>(lna, bm, ldt, abar, a64, bbar);
    k_fused<<<dim3(C4, B_), 256, 0, stream>>>(x, bbar, abar, a64, z0,
                                              e64, flags, out);
}

// Round 10
// 57.897 us; speedup vs baseline: 3.6231x; 3.6231x over previous
//
#include <hip/hip_runtime.h>
#include <hip/hip_bf16.h>

// Problem constants (S4Layer: T=4096, B=16, D=128, S=256)
#define T_  4096
#define B_  16
#define D_  128
#define S_  256
#define WND 64             // chunk length = GEMM t-tile
#define C4  (T_/WND)       // 64 chunks

using bf8   = __attribute__((ext_vector_type(8))) short;   // 8 bf16 (4 VGPRs)
using f32x4 = __attribute__((ext_vector_type(4))) float;   // MFMA acc

__device__ inline float bfbits(unsigned short h) {
    return __builtin_bit_cast(float, (unsigned)h << 16);
}
__device__ inline unsigned short bf16bits(float f) {
    return __hip_bfloat16_raw(__float2bfloat16(f)).x;
}

// Per-s discretization params, recomputed identically in both kernels
// (same ops, same input bits -> bit-identical results; matches old k_params).
struct SP { float ratio, abar; };
__device__ inline SP sparams(const float* __restrict__ lna,
                             const float* __restrict__ ldt, int s) {
    float la = fminf(fmaxf(lna[s], -8.f), 4.f);
    float ar = -expf(la);
    float lt = fminf(fmaxf(ldt[s], -8.f), 1.f);
    float dt = expf(lt);
    float xx = dt * ar;
    SP p;
    p.abar  = expf(xx);
    p.ratio = (fabsf(xx) < 1e-6f) ? dt : (expm1f(xx) / ar);
    return p;
}

// Load 8 fp32 from bmat, scale by ratio, pack to 8 bf16 (same rounding as
// the old k_params path: bf16(ratio * bmat)).
__device__ inline bf8 scale_pack8(const float* __restrict__ p, float r) {
    float4 v0 = *(const float4*)p;
    float4 v1 = *(const float4*)(p + 4);
    __hip_bfloat162 p0 = __float22bfloat162_rn(make_float2(v0.x * r, v0.y * r));
    __hip_bfloat162 p1 = __float22bfloat162_rn(make_float2(v0.z * r, v0.w * r));
    __hip_bfloat162 p2 = __float22bfloat162_rn(make_float2(v1.x * r, v1.y * r));
    __hip_bfloat162 p3 = __float22bfloat162_rn(make_float2(v1.z * r, v1.w * r));
    uint4 uu = make_uint4(*(unsigned*)&p0, *(unsigned*)&p1,
                          *(unsigned*)&p2, *(unsigned*)&p3);
    return __builtin_bit_cast(bf8, uu);
}

// ---------------- K1: GEMM + e64 -> ub[b][t][s] (bf16) ---------------------
// Block (c,b): 64t x 256s tile. B-fragments built from bmat on the fly;
// e64 Horner straight from bf16-rounded acc; LDS-transposed epilogue emits
// ONE contiguous 32 KiB run. 1024 blocks, 5 blocks/CU.
__global__ __launch_bounds__(256, 5) void k_gemm(
        const float* __restrict__ x, const float* __restrict__ bmat,
        const float* __restrict__ lna, const float* __restrict__ ldt,
        __hip_bfloat16* __restrict__ ub, float* __restrict__ e64) {
    const int c = blockIdx.x, b = blockIdx.y;
    __shared__ char LDS[WND * 512];    // 32 KiB: A-stage in [0,16K), then P
    const int tid = threadIdx.x, lane = tid & 63, w = tid >> 6;
    const int l15 = lane & 15, l4 = lane >> 4;

    // Stage A: rows t'=0..63 of batch b, fp32 -> bf16, swizzle ^((row&7)<<4)
#pragma unroll
    for (int k = 0; k < 8; ++k) {
        int idx = tid + k * 256;
        int row = idx >> 5, seg = idx & 31;
        float4 v = *(const float4*)(x + ((size_t)(c * WND + row) * B_ + b) * D_ + seg * 4);
        __hip_bfloat162 lo = __float22bfloat162_rn(make_float2(v.x, v.y));
        __hip_bfloat162 hi = __float22bfloat162_rn(make_float2(v.z, v.w));
        uint2 pk = { *(unsigned*)&lo, *(unsigned*)&hi };
        int off = (row * 256 + seg * 8) ^ ((row & 7) << 4);
        *(uint2*)(LDS + off) = pk;
    }
    __syncthreads();

    // MFMA: wave w owns s in [w*64,(w+1)*64); acc row = i*16 + l4*4 + r
    float abj[4];
    f32x4 acc[4][4] = {};
    for (int j = 0; j < 4; ++j) {
        int s = w * 64 + j * 16 + l15;
        SP pp = sparams(lna, ldt, s);
        abj[j] = pp.abar;
        bf8 bfrag[4];
#pragma unroll
        for (int kk = 0; kk < 4; ++kk)
            bfrag[kk] = scale_pack8(bmat + s * D_ + kk * 32 + l4 * 8, pp.ratio);
#pragma unroll
        for (int i = 0; i < 4; ++i) {
            bf8 af[4];
            int tr = i * 16 + l15;
#pragma unroll
            for (int kk = 0; kk < 4; ++kk) {
                int off = (tr * 256 + kk * 64 + l4 * 16) ^ ((tr & 7) << 4);
                af[kk] = *(const bf8*)(LDS + off);
            }
#pragma unroll
            for (int kk = 0; kk < 4; ++kk)
                acc[i][j] = __builtin_amdgcn_mfma_f32_16x16x32_bf16(
                                af[kk], bfrag[kk], acc[i][j], 0, 0, 0);
        }
    }
    __syncthreads();   // all A reads done; LDS becomes P[t'][s] bf16

    // e64 Horner (bf16-rounded, matches scan input) + P -> LDS (swizzled).
    // t' = i*16 + l4*4 + r ; weight a^(63-t') = a^(3-r)*a^(16(3-i))*a^(4(3-l4))
#pragma unroll
    for (int j = 0; j < 4; ++j) {
        int s = w * 64 + j * 16 + l15;
        float a  = abj[j];
        float a2 = a * a, a4 = a2 * a2, a8 = a4 * a4, a16 = a8 * a8;
        float lf = (l4 == 0) ? a8 * a4 : (l4 == 1) ? a8 : (l4 == 2) ? a4 : 1.f;
        float e = 0.f;
#pragma unroll
        for (int i = 0; i < 4; ++i) {
            unsigned short h0 = bf16bits(acc[i][j][0]);
            unsigned short h1 = bf16bits(acc[i][j][1]);
            unsigned short h2 = bf16bits(acc[i][j][2]);
            unsigned short h3 = bf16bits(acc[i][j][3]);
            float inner = bfbits(h0);
            inner = fmaf(inner, a, bfbits(h1));
            inner = fmaf(inner, a, bfbits(h2));
            inner = fmaf(inner, a, bfbits(h3));
            e = fmaf(e, a16, inner);
            int row0 = i * 16 + l4 * 4;            // ((row>>2)&3) == l4 here
            *(unsigned short*)(LDS + (((row0    ) * 512 + s * 2) ^ (l4 << 5))) = h0;
            *(unsigned short*)(LDS + (((row0 + 1) * 512 + s * 2) ^ (l4 << 5))) = h1;
            *(unsigned short*)(LDS + (((row0 + 2) * 512 + s * 2) ^ (l4 << 5))) = h2;
            *(unsigned short*)(LDS + (((row0 + 3) * 512 + s * 2) ^ (l4 << 5))) = h3;
        }
        e *= lf;
        e += __shfl_xor(e, 16);
        e += __shfl_xor(e, 32);
        if (l4 == 0) e64[((size_t)c * B_ + b) * S_ + s] = e;
    }
    __syncthreads();

    // Flat copy: ONE contiguous 32 KiB run -> ub[b][c*64 .. c*64+63][*]
    char* op = (char*)(ub + ((size_t)b * T_ + c * WND) * S_);
#pragma unroll
    for (int k = 0; k < 8; ++k) {
        int o = k * 4096 + tid * 16;
        int swz = (2 * k + (w >> 1)) & 3;          // = ((o>>11)&3)
        uint4 v = *(uint4*)(LDS + (o ^ (swz << 5)));
        *(uint4*)(op + o) = v;
    }
}

// ---------------- K2: fused carry + per-chunk scan + out -------------------
// Block (c,b), thread = s. Carry-in via fixed-trip predicated Horner over
// e64 partials (L2-hot, batch-16 loads). 1024 blocks x 4 waves = 16 waves/CU.
__global__ __launch_bounds__(256) void k_scan(
        const __hip_bfloat16* __restrict__ ub, const float* __restrict__ e64,
        const float* __restrict__ lna, const float* __restrict__ ldt,
        const float* __restrict__ z0, float* __restrict__ out) {
    const int c = blockIdx.x, b = blockIdx.y, s = threadIdx.x;
    SP pp = sparams(lna, ldt, s);
    const float a = pp.abar;
    float aw = a;                      // a^64 by squaring (same seq as before)
#pragma unroll
    for (int j = 0; j < 6; ++j) aw *= aw;

    float z = z0[b * S_ + s];
#pragma unroll
    for (int cp0 = 0; cp0 < C4; cp0 += 16) {
        float ev[16];
#pragma unroll
        for (int k = 0; k < 16; ++k)
            ev[k] = e64[((size_t)(cp0 + k) * B_ + b) * S_ + s];
#pragma unroll
        for (int k = 0; k < 16; ++k) {
            float zn = fmaf(aw, z, ev[k]);
            z = (cp0 + k < c) ? zn : z;         // garbage beyond c discarded
        }
    }

    const __hip_bfloat16* up = ub + ((size_t)b * T_ + c * WND) * S_ + s;
    float* op = out + ((size_t)(c * WND) * B_ + b) * S_ + s;
#pragma unroll 16
    for (int t = 0; t < WND; ++t) {
        z = fmaf(a, z, __bfloat162float(*up));
        __builtin_nontemporal_store(z, op);
        up += S_;
        op += (size_t)B_ * S_;
    }
}

extern "C" void kernel_launch(void* const* d_in, const int* in_sizes, int n_in,
                              void* d_out, int out_size, void* d_ws, size_t ws_size,
                              hipStream_t stream) {
    const float* x   = (const float*)d_in[0];  // [T,B,D]
    const float* z0  = (const float*)d_in[1];  // [B,S]
    const float* lna = (const float*)d_in[2];  // [S]
    const float* bm  = (const float*)d_in[3];  // [S,D]
    const float* ldt = (const float*)d_in[4];  // [S]
    float* out = (float*)d_out;

    char* ws = (char*)d_ws;
    float*          e64 = (float*)(ws + (128 << 10));       // 1 MiB [c][b][s]
    __hip_bfloat16* ub  = (__hip_bfloat16*)(ws + (4 << 20)); // 32 MiB [b][t][s]

    k_gemm<<<dim3(C4, B_), 256, 0, stream>>>(x, bm, lna, ldt, ub, e64);
    k_scan<<<dim3(C4, B_), 256, 0, stream>>>(ub, e64, lna, ldt, z0, out);
}